// Round 1
// baseline (663.164 us; speedup 1.0000x reference)
//
#include <hip/hip_runtime.h>

// Masked Sinkhorn, B=64, N=M=1024, fp32, 10 alternating normalization iters.
// Strategy: fused passes. Each iteration applies the current normalization
// (multiply by precomputed reciprocal denominators) AND accumulates the
// reductions needed for the next iteration. No atomics -> deterministic.

namespace {
constexpr int B_ = 64;
constexpr int N_ = 1024;
constexpr int M_ = 1024;
constexpr float EPS_ = 1e-4f;
constexpr int PCHUNK = 16;        // row chunks for column-sum partials
constexpr int RPC = N_ / PCHUNK;  // 64 rows per chunk
}

// ---------------------------------------------------------------------------
// Pre-pass: partial column sums of (s + EPS) over valid rows.
// grid (PCHUNK, B), block 256. Thread owns 4 consecutive cols (float4).
__global__ void colsum0_partial(const float* __restrict__ in,
                                const int* __restrict__ nrows,
                                float* __restrict__ partial) {
    const int b = blockIdx.y, p = blockIdx.x;
    const int nr = nrows[b];
    const int c0 = threadIdx.x * 4;
    const int rbeg = p * RPC;
    const int rend = min(rbeg + RPC, nr);
    float ax = 0.f, ay = 0.f, az = 0.f, aw = 0.f;
    const float* base = in + (size_t)b * N_ * M_;
    for (int n = rbeg; n < rend; ++n) {
        const float4 v = *reinterpret_cast<const float4*>(base + (size_t)n * M_ + c0);
        ax += v.x + EPS_; ay += v.y + EPS_; az += v.z + EPS_; aw += v.w + EPS_;
    }
    float4 o; o.x = ax; o.y = ay; o.z = az; o.w = aw;
    *reinterpret_cast<float4*>(partial + ((size_t)b * PCHUNK + p) * M_ + c0) = o;
}

// ---------------------------------------------------------------------------
// Reduce PCHUNK partials -> reciprocal column denominators (with ==0 guard).
// grid (M/256, B), block 256.
__global__ void reduce_colsum(const float* __restrict__ partial,
                              float* __restrict__ inv_colsum) {
    const int b = blockIdx.y;
    const int m = blockIdx.x * 256 + threadIdx.x;
    const float* p = partial + (size_t)b * PCHUNK * M_ + m;
    float s = 0.f;
#pragma unroll
    for (int i = 0; i < PCHUNK; ++i) s += p[(size_t)i * M_];
    inv_colsum[b * M_ + m] = (s == 0.f) ? 1.f : 1.f / s;
}

// ---------------------------------------------------------------------------
// Even iteration: divide by column denominators, produce reciprocal row sums.
// Wave-per-row: block 256 = 4 waves, each wave handles 4 rows.
// grid (N/16, B), block 256.
template <bool FIRST>
__global__ void even_pass(const float* __restrict__ src,
                          float* __restrict__ work,
                          const float* __restrict__ inv_colsum,
                          float* __restrict__ inv_rowsum,
                          const int* __restrict__ nrows,
                          const int* __restrict__ ncols) {
    const int b = blockIdx.y;
    const int nr = nrows[b], nc = ncols[b];
    const int wave = threadIdx.x >> 6;
    const int lane = threadIdx.x & 63;

    // Preload this lane's 16 inv_colsum values (same for every row).
    const float* icb = inv_colsum + b * M_;
    float4 ic[4];
#pragma unroll
    for (int t = 0; t < 4; ++t)
        ic[t] = *reinterpret_cast<const float4*>(icb + t * 256 + lane * 4);

    const int row0 = blockIdx.x * 16 + wave * 4;
    float* wb = work + (size_t)b * N_ * M_;
    const float* sb = src + (size_t)b * N_ * M_;

    for (int i = 0; i < 4; ++i) {
        const int n = row0 + i;
        const bool vr = (n < nr);
        if (!vr) {
            if (FIRST) {  // write zeros once; later passes never touch these rows
                float4 z; z.x = z.y = z.z = z.w = 0.f;
#pragma unroll
                for (int t = 0; t < 4; ++t)
                    *reinterpret_cast<float4*>(wb + (size_t)n * M_ + t * 256 + lane * 4) = z;
            }
            continue;
        }
        float acc = 0.f;
#pragma unroll
        for (int t = 0; t < 4; ++t) {
            const int m0 = t * 256 + lane * 4;
            if (m0 >= nc) {
                if (FIRST) {
                    float4 z; z.x = z.y = z.z = z.w = 0.f;
                    *reinterpret_cast<float4*>(wb + (size_t)n * M_ + m0) = z;
                }
                continue;  // non-FIRST: already zero, skip load+store
            }
            float4 v = *reinterpret_cast<const float4*>(sb + (size_t)n * M_ + m0);
            if (FIRST) { v.x += EPS_; v.y += EPS_; v.z += EPS_; v.w += EPS_; }
            float4 o;
            o.x = (m0 + 0 < nc) ? v.x * ic[t].x : 0.f;
            o.y = (m0 + 1 < nc) ? v.y * ic[t].y : 0.f;
            o.z = (m0 + 2 < nc) ? v.z * ic[t].z : 0.f;
            o.w = (m0 + 3 < nc) ? v.w * ic[t].w : 0.f;
            *reinterpret_cast<float4*>(wb + (size_t)n * M_ + m0) = o;
            acc += o.x + o.y + o.z + o.w;
        }
        // full-wave (64 lane) reduction
#pragma unroll
        for (int off = 1; off < 64; off <<= 1)
            acc += __shfl_xor(acc, off, 64);
        if (lane == 0)
            inv_rowsum[b * N_ + n] = (acc == 0.f) ? 1.f : 1.f / acc;
    }
}

// ---------------------------------------------------------------------------
// Odd iteration: divide by row denominators, produce column-sum partials.
// Column-stripe: thread owns 4 consecutive cols, block covers a 64-row chunk.
// grid (PCHUNK, B), block 256.
template <bool LAST>
__global__ void odd_pass(float* __restrict__ work,
                         const float* __restrict__ inv_rowsum,
                         float* __restrict__ partial,
                         const int* __restrict__ nrows,
                         const int* __restrict__ ncols) {
    const int b = blockIdx.y, p = blockIdx.x;
    const int nr = nrows[b], nc = ncols[b];
    const int c0 = threadIdx.x * 4;
    float ax = 0.f, ay = 0.f, az = 0.f, aw = 0.f;

    if (c0 < nc) {
        float* wb = work + (size_t)b * N_ * M_;
        const float* irb = inv_rowsum + b * N_;
        const int rbeg = p * RPC;
        const int rend = min(rbeg + RPC, nr);
        const bool fx = (c0 + 0 < nc), fy = (c0 + 1 < nc),
                   fz = (c0 + 2 < nc), fw = (c0 + 3 < nc);
        for (int n = rbeg; n < rend; ++n) {
            const float ir = irb[n];
            float4 v = *reinterpret_cast<float4*>(wb + (size_t)n * M_ + c0);
            float4 o;
            o.x = fx ? v.x * ir : 0.f;
            o.y = fy ? v.y * ir : 0.f;
            o.z = fz ? v.z * ir : 0.f;
            o.w = fw ? v.w * ir : 0.f;
            *reinterpret_cast<float4*>(wb + (size_t)n * M_ + c0) = o;
            ax += o.x; ay += o.y; az += o.z; aw += o.w;
        }
    }
    if (!LAST) {
        float4 o; o.x = ax; o.y = ay; o.z = az; o.w = aw;
        *reinterpret_cast<float4*>(partial + ((size_t)b * PCHUNK + p) * M_ + c0) = o;
    }
}

// ---------------------------------------------------------------------------
extern "C" void kernel_launch(void* const* d_in, const int* in_sizes, int n_in,
                              void* d_out, int out_size, void* d_ws, size_t ws_size,
                              hipStream_t stream) {
    const float* s = (const float*)d_in[0];
    const int* nrows = (const int*)d_in[1];
    const int* ncols = (const int*)d_in[2];
    float* work = (float*)d_out;

    float* partial = (float*)d_ws;                          // B*PCHUNK*M floats (4 MB)
    float* inv_col = partial + (size_t)B_ * PCHUNK * M_;    // B*M floats
    float* inv_row = inv_col + (size_t)B_ * M_;             // B*N floats

    const dim3 blk(256);

    // iter 0 denominators: column sums of (s+EPS) over valid rows
    colsum0_partial<<<dim3(PCHUNK, B_), blk, 0, stream>>>(s, nrows, partial);
    reduce_colsum<<<dim3(M_ / 256, B_), blk, 0, stream>>>(partial, inv_col);

    // iter 0 (even): col-normalize, produce row sums for iter 1
    even_pass<true><<<dim3(N_ / 16, B_), blk, 0, stream>>>(s, work, inv_col, inv_row, nrows, ncols);

    // iters 1..8 in (odd, even) pairs
    for (int k = 1; k <= 7; k += 2) {
        odd_pass<false><<<dim3(PCHUNK, B_), blk, 0, stream>>>(work, inv_row, partial, nrows, ncols);
        reduce_colsum<<<dim3(M_ / 256, B_), blk, 0, stream>>>(partial, inv_col);
        even_pass<false><<<dim3(N_ / 16, B_), blk, 0, stream>>>(work, work, inv_col, inv_row, nrows, ncols);
    }

    // iter 9 (odd, last): row-normalize only
    odd_pass<true><<<dim3(PCHUNK, B_), blk, 0, stream>>>(work, inv_row, partial, nrows, ncols);
}

// Round 2
// 392.661 us; speedup vs baseline: 1.6889x; 1.6889x over previous
//
#include <hip/hip_runtime.h>

// Masked Sinkhorn reformulated as alternating matvecs with diagonal scalings.
// State after any number of iterations is  A ∘ (r c^T)  on the valid block,
// A = s + EPS (read-only). Iterations:
//   c <- 1 / (A^T r)   (even iters; r=1 initially)
//   r <- 1 / (A  c)    (odd iters)
// Output: out[n,m] = A[n,m]*r[n]*c[m] for n<nr, m<nc; else 0.
// The big matrix is only READ during iterations (valid region ~144MB avg,
// L3-resident); the single 256MB write happens once at the end.

namespace {
constexpr int B_ = 64;
constexpr int N_ = 1024;
constexpr int M_ = 1024;
constexpr float EPS_ = 1e-4f;
constexpr int PCHUNK = 16;        // row chunks for column-sum partials
constexpr int RPC = N_ / PCHUNK;  // 64 rows per chunk
}

// ---------------------------------------------------------------------------
// Weighted column-sum partials: partial[b,p,m] = sum_{n in chunk, n<nr} (s+EPS)[n,m]*r[n]
// grid (PCHUNK, B), block 256; thread owns 4 consecutive cols (float4 reads).
template <bool INIT>  // INIT: r == 1 (iteration 0)
__global__ void colsum_partial(const float* __restrict__ s,
                               const float* __restrict__ r,
                               float* __restrict__ partial,
                               const int* __restrict__ nrows,
                               const int* __restrict__ ncols) {
    const int b = blockIdx.y, p = blockIdx.x;
    const int nr = nrows[b], nc = ncols[b];
    const int c0 = threadIdx.x * 4;
    float ax = 0.f, ay = 0.f, az = 0.f, aw = 0.f;
    if (c0 < nc) {
        const float* sb = s + (size_t)b * N_ * M_;
        const float* rb = r + b * N_;
        const int rbeg = p * RPC;
        const int rend = min(rbeg + RPC, nr);
        float sir = 0.f;  // sum of r over processed rows (EPS term hoisted)
        for (int n = rbeg; n < rend; ++n) {
            const float ir = INIT ? 1.f : rb[n];  // uniform across block -> scalar load
            const float4 v = *reinterpret_cast<const float4*>(sb + (size_t)n * M_ + c0);
            ax = fmaf(v.x, ir, ax); ay = fmaf(v.y, ir, ay);
            az = fmaf(v.z, ir, az); aw = fmaf(v.w, ir, aw);
            sir += ir;
        }
        const float e = EPS_ * sir;
        ax += e; ay += e; az += e; aw += e;
    }
    float4 o; o.x = ax; o.y = ay; o.z = az; o.w = aw;
    *reinterpret_cast<float4*>(partial + ((size_t)b * PCHUNK + p) * M_ + c0) = o;
}

// ---------------------------------------------------------------------------
// Reduce PCHUNK partials -> c[m] = 1/colsum. grid (M/256, B), block 256.
__global__ void reduce_colsum(const float* __restrict__ partial,
                              float* __restrict__ c) {
    const int b = blockIdx.y;
    const int m = blockIdx.x * 256 + threadIdx.x;
    const float* p = partial + (size_t)b * PCHUNK * M_ + m;
    float s = 0.f;
#pragma unroll
    for (int i = 0; i < PCHUNK; ++i) s += p[(size_t)i * M_];
    c[b * M_ + m] = (s == 0.f) ? 1.f : 1.f / s;  // guard unreachable (all terms > 0)
}

// ---------------------------------------------------------------------------
// Weighted row sums -> r[n] = 1/(A c)[n]. Wave-per-row, 4 rows per wave.
// grid (N/16, B), block 256 (4 waves).
__global__ void rowsum_pass(const float* __restrict__ s,
                            const float* __restrict__ c,
                            float* __restrict__ r,
                            const int* __restrict__ nrows,
                            const int* __restrict__ ncols) {
    const int b = blockIdx.y;
    const int nr = nrows[b], nc = ncols[b];
    const int wave = threadIdx.x >> 6, lane = threadIdx.x & 63;

    // Preload this lane's 16 c values, masked to 0 for m >= nc.
    const float* cb = c + b * M_;
    float4 cm[4];
    float csum = 0.f;  // per-lane partial of sum(c) -> EPS term
#pragma unroll
    for (int t = 0; t < 4; ++t) {
        const int m0 = t * 256 + lane * 4;
        float4 v = *reinterpret_cast<const float4*>(cb + m0);
        v.x = (m0 + 0 < nc) ? v.x : 0.f;
        v.y = (m0 + 1 < nc) ? v.y : 0.f;
        v.z = (m0 + 2 < nc) ? v.z : 0.f;
        v.w = (m0 + 3 < nc) ? v.w : 0.f;
        cm[t] = v;
        csum += v.x + v.y + v.z + v.w;
    }
    const int ntiles = (nc + 255) >> 8;  // >=2 since nc>=512
    const int row0 = blockIdx.x * 16 + wave * 4;
    const float* sb = s + (size_t)b * N_ * M_;

    for (int i = 0; i < 4; ++i) {
        const int n = row0 + i;
        if (n >= nr) continue;
        float acc = EPS_ * csum;  // per-lane; reduces to EPS * sum(c) over wave
#pragma unroll
        for (int t = 0; t < 4; ++t) {
            if (t < ntiles) {
                const int m0 = t * 256 + lane * 4;
                const float4 v = *reinterpret_cast<const float4*>(sb + (size_t)n * M_ + m0);
                acc = fmaf(v.x, cm[t].x, acc); acc = fmaf(v.y, cm[t].y, acc);
                acc = fmaf(v.z, cm[t].z, acc); acc = fmaf(v.w, cm[t].w, acc);
            }
        }
#pragma unroll
        for (int off = 1; off < 64; off <<= 1)
            acc += __shfl_xor(acc, off, 64);
        if (lane == 0)
            r[b * N_ + n] = (acc == 0.f) ? 1.f : 1.f / acc;  // guard unreachable
    }
}

// ---------------------------------------------------------------------------
// Final: out[n,m] = (s+EPS)*r[n]*c[m] on valid block, else 0. Writes ALL of out.
// grid (N/16, B), block 256 (4 waves x 4 rows).
__global__ void final_pass(const float* __restrict__ s,
                           const float* __restrict__ r,
                           const float* __restrict__ c,
                           float* __restrict__ out,
                           const int* __restrict__ nrows,
                           const int* __restrict__ ncols) {
    const int b = blockIdx.y;
    const int nr = nrows[b], nc = ncols[b];
    const int wave = threadIdx.x >> 6, lane = threadIdx.x & 63;

    const float* cb = c + b * M_;
    float4 cm[4];
#pragma unroll
    for (int t = 0; t < 4; ++t) {
        const int m0 = t * 256 + lane * 4;
        float4 v = *reinterpret_cast<const float4*>(cb + m0);
        v.x = (m0 + 0 < nc) ? v.x : 0.f;
        v.y = (m0 + 1 < nc) ? v.y : 0.f;
        v.z = (m0 + 2 < nc) ? v.z : 0.f;
        v.w = (m0 + 3 < nc) ? v.w : 0.f;
        cm[t] = v;
    }
    const int ntiles = (nc + 255) >> 8;
    const int row0 = blockIdx.x * 16 + wave * 4;
    const float* sb = s + (size_t)b * N_ * M_;
    float* ob = out + (size_t)b * N_ * M_;

    for (int i = 0; i < 4; ++i) {
        const int n = row0 + i;
        const float4 z = {0.f, 0.f, 0.f, 0.f};
        if (n >= nr) {
#pragma unroll
            for (int t = 0; t < 4; ++t)
                *reinterpret_cast<float4*>(ob + (size_t)n * M_ + t * 256 + lane * 4) = z;
            continue;
        }
        const float rn = r[b * N_ + n];
#pragma unroll
        for (int t = 0; t < 4; ++t) {
            const int m0 = t * 256 + lane * 4;
            float4 o = z;
            if (t < ntiles) {
                const float4 v = *reinterpret_cast<const float4*>(sb + (size_t)n * M_ + m0);
                o.x = (v.x + EPS_) * rn * cm[t].x;
                o.y = (v.y + EPS_) * rn * cm[t].y;
                o.z = (v.z + EPS_) * rn * cm[t].z;
                o.w = (v.w + EPS_) * rn * cm[t].w;
            }
            *reinterpret_cast<float4*>(ob + (size_t)n * M_ + m0) = o;
        }
    }
}

// ---------------------------------------------------------------------------
extern "C" void kernel_launch(void* const* d_in, const int* in_sizes, int n_in,
                              void* d_out, int out_size, void* d_ws, size_t ws_size,
                              hipStream_t stream) {
    const float* s = (const float*)d_in[0];
    const int* nrows = (const int*)d_in[1];
    const int* ncols = (const int*)d_in[2];
    float* out = (float*)d_out;

    float* partial = (float*)d_ws;                        // B*PCHUNK*M floats (4 MB)
    float* c = partial + (size_t)B_ * PCHUNK * M_;        // B*M floats
    float* r = c + (size_t)B_ * M_;                       // B*N floats

    const dim3 blk(256);
    const dim3 g_col(PCHUNK, B_);
    const dim3 g_red(M_ / 256, B_);
    const dim3 g_row(N_ / 16, B_);

    // iter 0: c0 = 1/(A^T 1)
    colsum_partial<true><<<g_col, blk, 0, stream>>>(s, r, partial, nrows, ncols);
    reduce_colsum<<<g_red, blk, 0, stream>>>(partial, c);

    // iters 1..8: (r <- 1/(A c), c <- 1/(A^T r)) x 4
    for (int k = 0; k < 4; ++k) {
        rowsum_pass<<<g_row, blk, 0, stream>>>(s, c, r, nrows, ncols);
        colsum_partial<false><<<g_col, blk, 0, stream>>>(s, r, partial, nrows, ncols);
        reduce_colsum<<<g_red, blk, 0, stream>>>(partial, c);
    }

    // iter 9: r9 = 1/(A c8)
    rowsum_pass<<<g_row, blk, 0, stream>>>(s, c, r, nrows, ncols);

    // out = A * r9 * c8 on valid block, 0 elsewhere
    final_pass<<<g_row, blk, 0, stream>>>(s, r, c, out, nrows, ncols);
}

// Round 4
// 278.693 us; speedup vs baseline: 2.3796x; 1.4089x over previous
//
#include <hip/hip_runtime.h>

// Masked Sinkhorn as alternating matvecs with the read-only matrix A = s+EPS.
//   c <- 1/(A^T r), r <- 1/(A c);  out = A ∘ (r9 c8^T) on valid block.
// Key structure: each (rowsum -> colsum) iteration pair is ONE pass over s.
// Wave-per-row: the row tile stays in registers for both the dot (-> r_n via
// shuffle reduce) and the column-sum accumulation (s[n,m]*r_n). r is never
// materialized in global memory. 6 big reads + 1 big write total.

namespace {
constexpr int B_ = 64;
constexpr int N_ = 1024;
constexpr int M_ = 1024;
constexpr float EPS_ = 1e-4f;
constexpr int PCHUNK = 16;        // row chunks for column-sum partials
constexpr int RPC = N_ / PCHUNK;  // 64 rows per chunk
}

// ---------------------------------------------------------------------------
// Iter-0 column sums: partial[b,p,m] = sum_{n in chunk, n<nr} (s[n,m]+EPS)
// grid (PCHUNK, B), block 256; thread owns 4 consecutive cols.
__global__ void colsum0_partial(const float* __restrict__ s,
                                float* __restrict__ partial,
                                const int* __restrict__ nrows,
                                const int* __restrict__ ncols) {
    const int b = blockIdx.y, p = blockIdx.x;
    const int nr = nrows[b], nc = ncols[b];
    const int c0 = threadIdx.x * 4;
    float ax = 0.f, ay = 0.f, az = 0.f, aw = 0.f;
    if (c0 < nc) {
        const float* sb = s + (size_t)b * N_ * M_;
        const int rbeg = p * RPC;
        const int rend = min(rbeg + RPC, nr);
        for (int n = rbeg; n < rend; ++n) {
            const float4 v = *reinterpret_cast<const float4*>(sb + (size_t)n * M_ + c0);
            ax += v.x; ay += v.y; az += v.z; aw += v.w;
        }
        const float e = EPS_ * (float)max(rend - rbeg, 0);
        ax += e; ay += e; az += e; aw += e;
    }
    float4 o; o.x = ax; o.y = ay; o.z = az; o.w = aw;
    *reinterpret_cast<float4*>(partial + ((size_t)b * PCHUNK + p) * M_ + c0) = o;
}

// ---------------------------------------------------------------------------
// Reduce PCHUNK partials -> c[m] = 1/colsum. grid (M/256, B), block 256.
__global__ void reduce_colsum(const float* __restrict__ partial,
                              float* __restrict__ c) {
    const int b = blockIdx.y;
    const int m = blockIdx.x * 256 + threadIdx.x;
    const float* p = partial + (size_t)b * PCHUNK * M_ + m;
    float s = 0.f;
#pragma unroll
    for (int i = 0; i < PCHUNK; ++i) s += p[(size_t)i * M_];
    c[b * M_ + m] = (s == 0.f) ? 1.f : 1.f / s;  // guard unreachable (all terms > 0)
}

// ---------------------------------------------------------------------------
// Fused iteration pair: r = 1/(A c) and partial colsums of A^T r, one read.
// grid (PCHUNK, B), block 256 = 4 waves; wave handles 16 full rows.
// Lane owns cols {t*256 + lane*4 .. +3}, t=0..3 (full 1024-col coverage).
__global__ void fused_pair(const float* __restrict__ s,
                           const float* __restrict__ c,
                           float* __restrict__ partial,
                           const int* __restrict__ nrows,
                           const int* __restrict__ ncols) {
    __shared__ float lds[4][M_];
    const int b = blockIdx.y, p = blockIdx.x;
    const int nr = nrows[b], nc = ncols[b];
    const int wave = threadIdx.x >> 6, lane = threadIdx.x & 63;

    // Lane's 16 c values, masked to 0 beyond nc; csum -> EPS term of the dot.
    const float* cb = c + b * M_;
    float4 cm[4];
    float csum = 0.f;
#pragma unroll
    for (int t = 0; t < 4; ++t) {
        const int m0 = t * 256 + lane * 4;
        float4 v = *reinterpret_cast<const float4*>(cb + m0);
        v.x = (m0 + 0 < nc) ? v.x : 0.f;
        v.y = (m0 + 1 < nc) ? v.y : 0.f;
        v.z = (m0 + 2 < nc) ? v.z : 0.f;
        v.w = (m0 + 3 < nc) ? v.w : 0.f;
        cm[t] = v;
        csum += v.x + v.y + v.z + v.w;
    }
    const int ntiles = (nc + 255) >> 8;  // 2..4 since nc in [512,1024]

    float4 ca[4];  // per-lane column accumulators (sum_n s[n,m]*r_n)
#pragma unroll
    for (int t = 0; t < 4; ++t) ca[t] = float4{0.f, 0.f, 0.f, 0.f};
    float sr = 0.f;  // sum of r_n over this wave's valid rows -> EPS term

    const int rbeg = p * RPC + wave * 16;
    const int rend = min(rbeg + 16, nr);
    const float* sb = s + (size_t)b * N_ * M_;

    for (int n = rbeg; n < rend; ++n) {
        float4 v[4];
#pragma unroll
        for (int t = 0; t < 4; ++t) v[t] = float4{0.f, 0.f, 0.f, 0.f};
        float acc = EPS_ * csum;
#pragma unroll
        for (int t = 0; t < 4; ++t) {
            if (t < ntiles) {
                v[t] = *reinterpret_cast<const float4*>(sb + (size_t)n * M_ + t * 256 + lane * 4);
                acc = fmaf(v[t].x, cm[t].x, acc); acc = fmaf(v[t].y, cm[t].y, acc);
                acc = fmaf(v[t].z, cm[t].z, acc); acc = fmaf(v[t].w, cm[t].w, acc);
            }
        }
#pragma unroll
        for (int off = 1; off < 64; off <<= 1)
            acc += __shfl_xor(acc, off, 64);
        const float rn = 1.f / acc;  // acc >= 512*EPS*min(c) > 0
        sr += rn;
#pragma unroll
        for (int t = 0; t < 4; ++t) {
            ca[t].x = fmaf(v[t].x, rn, ca[t].x);
            ca[t].y = fmaf(v[t].y, rn, ca[t].y);
            ca[t].z = fmaf(v[t].z, rn, ca[t].z);
            ca[t].w = fmaf(v[t].w, rn, ca[t].w);
        }
    }
    // EPS * sum(r) term of the column sums (matters only for valid cols).
    {
        const float e = EPS_ * sr;
#pragma unroll
        for (int t = 0; t < 4; ++t) {
            ca[t].x += e; ca[t].y += e; ca[t].z += e; ca[t].w += e;
        }
    }
    // Combine the 4 waves' column partials through LDS -> partial[b,p,:].
#pragma unroll
    for (int t = 0; t < 4; ++t)
        *reinterpret_cast<float4*>(&lds[wave][t * 256 + lane * 4]) = ca[t];
    __syncthreads();
    const int m0 = threadIdx.x * 4;
    float4 a0 = *reinterpret_cast<const float4*>(&lds[0][m0]);
    float4 a1 = *reinterpret_cast<const float4*>(&lds[1][m0]);
    float4 a2 = *reinterpret_cast<const float4*>(&lds[2][m0]);
    float4 a3 = *reinterpret_cast<const float4*>(&lds[3][m0]);
    float4 o;
    o.x = a0.x + a1.x + a2.x + a3.x;
    o.y = a0.y + a1.y + a2.y + a3.y;
    o.z = a0.z + a1.z + a2.z + a3.z;
    o.w = a0.w + a1.w + a2.w + a3.w;
    *reinterpret_cast<float4*>(partial + ((size_t)b * PCHUNK + p) * M_ + m0) = o;
}

// ---------------------------------------------------------------------------
// Fused final: r9 = 1/(A c8) inline, then out = (s+EPS)*r9*c8 (cm mask zeroes
// invalid cols automatically); invalid rows -> zeros. Writes all of out.
// grid (N/16, B), block 256 = 4 waves x 4 rows.
__global__ void final_fused(const float* __restrict__ s,
                            const float* __restrict__ c,
                            float* __restrict__ out,
                            const int* __restrict__ nrows,
                            const int* __restrict__ ncols) {
    const int b = blockIdx.y;
    const int nr = nrows[b], nc = ncols[b];
    const int wave = threadIdx.x >> 6, lane = threadIdx.x & 63;

    const float* cb = c + b * M_;
    float4 cm[4];
    float csum = 0.f;
#pragma unroll
    for (int t = 0; t < 4; ++t) {
        const int m0 = t * 256 + lane * 4;
        float4 v = *reinterpret_cast<const float4*>(cb + m0);
        v.x = (m0 + 0 < nc) ? v.x : 0.f;
        v.y = (m0 + 1 < nc) ? v.y : 0.f;
        v.z = (m0 + 2 < nc) ? v.z : 0.f;
        v.w = (m0 + 3 < nc) ? v.w : 0.f;
        cm[t] = v;
        csum += v.x + v.y + v.z + v.w;
    }
    const int ntiles = (nc + 255) >> 8;
    const int row0 = blockIdx.x * 16 + wave * 4;
    const float* sb = s + (size_t)b * N_ * M_;
    float* ob = out + (size_t)b * N_ * M_;

    for (int i = 0; i < 4; ++i) {
        const int n = row0 + i;
        if (n >= nr) {
            const float4 z = {0.f, 0.f, 0.f, 0.f};
#pragma unroll
            for (int t = 0; t < 4; ++t)
                *reinterpret_cast<float4*>(ob + (size_t)n * M_ + t * 256 + lane * 4) = z;
            continue;
        }
        float4 v[4];
#pragma unroll
        for (int t = 0; t < 4; ++t) v[t] = float4{0.f, 0.f, 0.f, 0.f};
        float acc = EPS_ * csum;
#pragma unroll
        for (int t = 0; t < 4; ++t) {
            if (t < ntiles) {
                v[t] = *reinterpret_cast<const float4*>(sb + (size_t)n * M_ + t * 256 + lane * 4);
                acc = fmaf(v[t].x, cm[t].x, acc); acc = fmaf(v[t].y, cm[t].y, acc);
                acc = fmaf(v[t].z, cm[t].z, acc); acc = fmaf(v[t].w, cm[t].w, acc);
            }
        }
#pragma unroll
        for (int off = 1; off < 64; off <<= 1)
            acc += __shfl_xor(acc, off, 64);
        const float rn = 1.f / acc;
#pragma unroll
        for (int t = 0; t < 4; ++t) {
            float4 o;
            o.x = (v[t].x + EPS_) * rn * cm[t].x;  // cm=0 beyond nc -> 0
            o.y = (v[t].y + EPS_) * rn * cm[t].y;
            o.z = (v[t].z + EPS_) * rn * cm[t].z;
            o.w = (v[t].w + EPS_) * rn * cm[t].w;
            *reinterpret_cast<float4*>(ob + (size_t)n * M_ + t * 256 + lane * 4) = o;
        }
    }
}

// ---------------------------------------------------------------------------
extern "C" void kernel_launch(void* const* d_in, const int* in_sizes, int n_in,
                              void* d_out, int out_size, void* d_ws, size_t ws_size,
                              hipStream_t stream) {
    const float* s = (const float*)d_in[0];
    const int* nrows = (const int*)d_in[1];
    const int* ncols = (const int*)d_in[2];
    float* out = (float*)d_out;

    float* partial = (float*)d_ws;                  // B*PCHUNK*M floats (4 MB)
    float* c = partial + (size_t)B_ * PCHUNK * M_;  // B*M floats

    const dim3 blk(256);
    const dim3 g_chunk(PCHUNK, B_);
    const dim3 g_red(M_ / 256, B_);
    const dim3 g_fin(N_ / 16, B_);

    // iter 0: c0 = 1/(A^T 1)
    colsum0_partial<<<g_chunk, blk, 0, stream>>>(s, partial, nrows, ncols);
    reduce_colsum<<<g_red, blk, 0, stream>>>(partial, c);

    // iters (1,2), (3,4), (5,6), (7,8): one pass each
    for (int k = 0; k < 4; ++k) {
        fused_pair<<<g_chunk, blk, 0, stream>>>(s, c, partial, nrows, ncols);
        reduce_colsum<<<g_red, blk, 0, stream>>>(partial, c);
    }

    // iter 9 + output, one pass
    final_fused<<<g_fin, blk, 0, stream>>>(s, c, out, nrows, ncols);
}

// Round 5
// 277.109 us; speedup vs baseline: 2.3931x; 1.0057x over previous
//
#include <hip/hip_runtime.h>
#include <hip/hip_fp16.h>

// Masked Sinkhorn via diagonal-scaling algebra on A = s+EPS:
//   c <- 1/(A^T r), r <- 1/(A c), out = A ∘ (r9 c8^T) on valid block.
// R5: A is compressed ONCE to fp16 (q, <=134MB -> L3-resident); all iteration
// passes read q. Per-pass c-reduction folded into consumers (6 dispatches).
// Nontemporal: s reads (read-once) and out writes (don't evict q from L3).
// Fallback to the proven fp32 path if ws_size can't hold q.

namespace {
constexpr int B_ = 64;
constexpr int N_ = 1024;
constexpr int M_ = 1024;
constexpr float EPS_ = 1e-4f;
constexpr int PCHUNK = 16;        // row chunks for column-sum partials
constexpr int RPC = N_ / PCHUNK;  // 64 rows per chunk
}

typedef float f32x4_ __attribute__((ext_vector_type(4)));

__device__ __forceinline__ float4 nt_load4(const float* p) {
    f32x4_ v = __builtin_nontemporal_load(reinterpret_cast<const f32x4_*>(p));
    return float4{v.x, v.y, v.z, v.w};
}
__device__ __forceinline__ void nt_store4(float* p, float a, float b, float c, float d) {
    f32x4_ v = {a, b, c, d};
    __builtin_nontemporal_store(v, reinterpret_cast<f32x4_*>(p));
}

// ===========================================================================
// fp16 path
// ===========================================================================

// Prep: q = fp16(s+EPS) for valid rows (zeros for whole col-tiles beyond nc),
// plus iter-0 column-sum partials. grid (PCHUNK, B), block 256 = 4 waves x 16 rows.
__global__ void prep_pass(const float* __restrict__ s,
                          __half* __restrict__ q,
                          float* __restrict__ partial,
                          const int* __restrict__ nrows,
                          const int* __restrict__ ncols) {
    __shared__ float lds[4][M_];
    const int b = blockIdx.y, p = blockIdx.x;
    const int nr = nrows[b], nc = ncols[b];
    const int wave = threadIdx.x >> 6, lane = threadIdx.x & 63;

    float4 ca[4];
#pragma unroll
    for (int t = 0; t < 4; ++t) ca[t] = float4{0.f, 0.f, 0.f, 0.f};

    const int rbeg = p * RPC + wave * 16;
    const int rend = min(rbeg + 16, nr);
    const float* sb = s + (size_t)b * N_ * M_;
    __half* qb = q + (size_t)b * N_ * M_;

    for (int n = rbeg; n < rend; ++n) {
#pragma unroll
        for (int t = 0; t < 4; ++t) {
            const int m0 = t * 256 + lane * 4;
            float4 v = {0.f, 0.f, 0.f, 0.f};
            if (m0 < nc) {
                v = nt_load4(sb + (size_t)n * M_ + m0);
                v.x += EPS_; v.y += EPS_; v.z += EPS_; v.w += EPS_;
            }
            __half2 h01 = __floats2half2_rn(v.x, v.y);
            __half2 h23 = __floats2half2_rn(v.z, v.w);
            uint2 st;
            st.x = *reinterpret_cast<const unsigned*>(&h01);
            st.y = *reinterpret_cast<const unsigned*>(&h23);
            *reinterpret_cast<uint2*>(qb + (size_t)n * M_ + m0) = st;
            ca[t].x += v.x; ca[t].y += v.y; ca[t].z += v.z; ca[t].w += v.w;
        }
    }
#pragma unroll
    for (int t = 0; t < 4; ++t)
        *reinterpret_cast<float4*>(&lds[wave][t * 256 + lane * 4]) = ca[t];
    __syncthreads();
    const int m0 = threadIdx.x * 4;
    float4 a0 = *reinterpret_cast<const float4*>(&lds[0][m0]);
    float4 a1 = *reinterpret_cast<const float4*>(&lds[1][m0]);
    float4 a2 = *reinterpret_cast<const float4*>(&lds[2][m0]);
    float4 a3 = *reinterpret_cast<const float4*>(&lds[3][m0]);
    float4 o;
    o.x = a0.x + a1.x + a2.x + a3.x;
    o.y = a0.y + a1.y + a2.y + a3.y;
    o.z = a0.z + a1.z + a2.z + a3.z;
    o.w = a0.w + a1.w + a2.w + a3.w;
    *reinterpret_cast<float4*>(partial + ((size_t)b * PCHUNK + p) * M_ + m0) = o;
}

// Fused iteration pair, fp16: reduce partial_in -> c (in LDS, identical order
// in every block -> bitwise-consistent), then r = 1/(q c) per row and column
// partials of q^T r -> partial_out. grid (PCHUNK, B), block 256 = 4 waves x 16 rows.
// Lane owns cols {t*512 + lane*8 .. +7}, t=0,1.
__global__ void fused_pass_h(const __half* __restrict__ q,
                             const float* __restrict__ partial_in,
                             float* __restrict__ partial_out,
                             const int* __restrict__ nrows,
                             const int* __restrict__ ncols) {
    __shared__ float lds[4][M_];
    const int b = blockIdx.y, p = blockIdx.x;
    const int nr = nrows[b], nc = ncols[b];
    const int wave = threadIdx.x >> 6, lane = threadIdx.x & 63;

    // phase 1: c = 1/colsum into lds[0][.]
    {
        const int m0 = threadIdx.x * 4;
        const float* pp = partial_in + (size_t)b * PCHUNK * M_ + m0;
        float4 sacc = {0.f, 0.f, 0.f, 0.f};
#pragma unroll
        for (int i = 0; i < PCHUNK; ++i) {
            const float4 v = *reinterpret_cast<const float4*>(pp + (size_t)i * M_);
            sacc.x += v.x; sacc.y += v.y; sacc.z += v.z; sacc.w += v.w;
        }
        float4 cv;
        cv.x = (sacc.x == 0.f) ? 1.f : 1.f / sacc.x;
        cv.y = (sacc.y == 0.f) ? 1.f : 1.f / sacc.y;
        cv.z = (sacc.z == 0.f) ? 1.f : 1.f / sacc.z;
        cv.w = (sacc.w == 0.f) ? 1.f : 1.f / sacc.w;
        *reinterpret_cast<float4*>(&lds[0][m0]) = cv;
    }
    __syncthreads();

    // phase 2: lane's 16 c values, masked to 0 beyond nc
    float cm[16];
#pragma unroll
    for (int t = 0; t < 2; ++t)
#pragma unroll
        for (int j = 0; j < 8; ++j) {
            const int m = t * 512 + lane * 8 + j;
            const float v = lds[0][m];
            cm[t * 8 + j] = (m < nc) ? v : 0.f;
        }
    __syncthreads();  // lds reused for the column-partial combine below

    // phase 3: rows — dot -> r_n, accumulate q*r_n into column accumulators
    float ca[16];
#pragma unroll
    for (int k = 0; k < 16; ++k) ca[k] = 0.f;

    const int rbeg = p * RPC + wave * 16;
    const int rend = min(rbeg + 16, nr);
    const __half* qb = q + (size_t)b * N_ * M_;

    for (int n = rbeg; n < rend; ++n) {
        float f[16];
#pragma unroll
        for (int t = 0; t < 2; ++t) {
            const float4 raw = *reinterpret_cast<const float4*>(
                qb + (size_t)n * M_ + t * 512 + lane * 8);
            const __half2* hp = reinterpret_cast<const __half2*>(&raw);
#pragma unroll
            for (int k = 0; k < 4; ++k) {
                const float2 fr = __half22float2(hp[k]);
                f[t * 8 + 2 * k] = fr.x;
                f[t * 8 + 2 * k + 1] = fr.y;
            }
        }
        float acc = 0.f;
#pragma unroll
        for (int k = 0; k < 16; ++k) acc = fmaf(f[k], cm[k], acc);
#pragma unroll
        for (int off = 1; off < 64; off <<= 1)
            acc += __shfl_xor(acc, off, 64);
        const float rn = 1.f / acc;  // acc > 0 always (q,c > 0 on valid cols)
#pragma unroll
        for (int k = 0; k < 16; ++k) ca[k] = fmaf(f[k], rn, ca[k]);
    }

    // phase 4: combine 4 waves -> partial_out[b][p][:]
#pragma unroll
    for (int t = 0; t < 2; ++t) {
        float4 v0 = {ca[t * 8 + 0], ca[t * 8 + 1], ca[t * 8 + 2], ca[t * 8 + 3]};
        float4 v1 = {ca[t * 8 + 4], ca[t * 8 + 5], ca[t * 8 + 6], ca[t * 8 + 7]};
        *reinterpret_cast<float4*>(&lds[wave][t * 512 + lane * 8]) = v0;
        *reinterpret_cast<float4*>(&lds[wave][t * 512 + lane * 8 + 4]) = v1;
    }
    __syncthreads();
    const int m0 = threadIdx.x * 4;
    float4 a0 = *reinterpret_cast<const float4*>(&lds[0][m0]);
    float4 a1 = *reinterpret_cast<const float4*>(&lds[1][m0]);
    float4 a2 = *reinterpret_cast<const float4*>(&lds[2][m0]);
    float4 a3 = *reinterpret_cast<const float4*>(&lds[3][m0]);
    float4 o;
    o.x = a0.x + a1.x + a2.x + a3.x;
    o.y = a0.y + a1.y + a2.y + a3.y;
    o.z = a0.z + a1.z + a2.z + a3.z;
    o.w = a0.w + a1.w + a2.w + a3.w;
    *reinterpret_cast<float4*>(partial_out + ((size_t)b * PCHUNK + p) * M_ + m0) = o;
}

// Final: reduce partial_in -> c8, r9 = 1/(q c8) inline, out = q*r9*c8 (fp32,
// nontemporal); invalid rows/cols -> 0. grid (PCHUNK, B), block 256 = 4w x 16r.
__global__ void final_pass_h(const __half* __restrict__ q,
                             const float* __restrict__ partial_in,
                             float* __restrict__ out,
                             const int* __restrict__ nrows,
                             const int* __restrict__ ncols) {
    __shared__ float ldsc[M_];
    const int b = blockIdx.y, p = blockIdx.x;
    const int nr = nrows[b], nc = ncols[b];
    const int wave = threadIdx.x >> 6, lane = threadIdx.x & 63;

    {
        const int m0 = threadIdx.x * 4;
        const float* pp = partial_in + (size_t)b * PCHUNK * M_ + m0;
        float4 sacc = {0.f, 0.f, 0.f, 0.f};
#pragma unroll
        for (int i = 0; i < PCHUNK; ++i) {
            const float4 v = *reinterpret_cast<const float4*>(pp + (size_t)i * M_);
            sacc.x += v.x; sacc.y += v.y; sacc.z += v.z; sacc.w += v.w;
        }
        float4 cv;
        cv.x = (sacc.x == 0.f) ? 1.f : 1.f / sacc.x;
        cv.y = (sacc.y == 0.f) ? 1.f : 1.f / sacc.y;
        cv.z = (sacc.z == 0.f) ? 1.f : 1.f / sacc.z;
        cv.w = (sacc.w == 0.f) ? 1.f : 1.f / sacc.w;
        *reinterpret_cast<float4*>(&ldsc[m0]) = cv;
    }
    __syncthreads();

    float cm[16];
#pragma unroll
    for (int t = 0; t < 2; ++t)
#pragma unroll
        for (int j = 0; j < 8; ++j) {
            const int m = t * 512 + lane * 8 + j;
            const float v = ldsc[m];
            cm[t * 8 + j] = (m < nc) ? v : 0.f;
        }

    const int rbeg = p * RPC + wave * 16;
    const __half* qb = q + (size_t)b * N_ * M_;
    float* ob = out + (size_t)b * N_ * M_;

    for (int n = rbeg; n < rbeg + 16; ++n) {
        if (n >= nr) {  // zero row (wave-uniform branch)
#pragma unroll
            for (int t = 0; t < 2; ++t) {
                nt_store4(ob + (size_t)n * M_ + t * 512 + lane * 8, 0.f, 0.f, 0.f, 0.f);
                nt_store4(ob + (size_t)n * M_ + t * 512 + lane * 8 + 4, 0.f, 0.f, 0.f, 0.f);
            }
            continue;
        }
        float f[16];
#pragma unroll
        for (int t = 0; t < 2; ++t) {
            const float4 raw = *reinterpret_cast<const float4*>(
                qb + (size_t)n * M_ + t * 512 + lane * 8);
            const __half2* hp = reinterpret_cast<const __half2*>(&raw);
#pragma unroll
            for (int k = 0; k < 4; ++k) {
                const float2 fr = __half22float2(hp[k]);
                f[t * 8 + 2 * k] = fr.x;
                f[t * 8 + 2 * k + 1] = fr.y;
            }
        }
        float acc = 0.f;
#pragma unroll
        for (int k = 0; k < 16; ++k) acc = fmaf(f[k], cm[k], acc);
#pragma unroll
        for (int off = 1; off < 64; off <<= 1)
            acc += __shfl_xor(acc, off, 64);
        const float rn = 1.f / acc;
#pragma unroll
        for (int t = 0; t < 2; ++t) {
            nt_store4(ob + (size_t)n * M_ + t * 512 + lane * 8,
                      f[t * 8 + 0] * rn * cm[t * 8 + 0],
                      f[t * 8 + 1] * rn * cm[t * 8 + 1],
                      f[t * 8 + 2] * rn * cm[t * 8 + 2],
                      f[t * 8 + 3] * rn * cm[t * 8 + 3]);
            nt_store4(ob + (size_t)n * M_ + t * 512 + lane * 8 + 4,
                      f[t * 8 + 4] * rn * cm[t * 8 + 4],
                      f[t * 8 + 5] * rn * cm[t * 8 + 5],
                      f[t * 8 + 6] * rn * cm[t * 8 + 6],
                      f[t * 8 + 7] * rn * cm[t * 8 + 7]);
        }
    }
}

// ===========================================================================
// fp32 fallback (proven R4 path), used when ws_size can't hold q.
// ===========================================================================

__global__ void colsum0_partial(const float* __restrict__ s,
                                float* __restrict__ partial,
                                const int* __restrict__ nrows,
                                const int* __restrict__ ncols) {
    const int b = blockIdx.y, p = blockIdx.x;
    const int nr = nrows[b], nc = ncols[b];
    const int c0 = threadIdx.x * 4;
    float ax = 0.f, ay = 0.f, az = 0.f, aw = 0.f;
    if (c0 < nc) {
        const float* sb = s + (size_t)b * N_ * M_;
        const int rbeg = p * RPC;
        const int rend = min(rbeg + RPC, nr);
        for (int n = rbeg; n < rend; ++n) {
            const float4 v = *reinterpret_cast<const float4*>(sb + (size_t)n * M_ + c0);
            ax += v.x; ay += v.y; az += v.z; aw += v.w;
        }
        const float e = EPS_ * (float)max(rend - rbeg, 0);
        ax += e; ay += e; az += e; aw += e;
    }
    float4 o; o.x = ax; o.y = ay; o.z = az; o.w = aw;
    *reinterpret_cast<float4*>(partial + ((size_t)b * PCHUNK + p) * M_ + c0) = o;
}

__global__ void reduce_colsum(const float* __restrict__ partial,
                              float* __restrict__ c) {
    const int b = blockIdx.y;
    const int m = blockIdx.x * 256 + threadIdx.x;
    const float* p = partial + (size_t)b * PCHUNK * M_ + m;
    float s = 0.f;
#pragma unroll
    for (int i = 0; i < PCHUNK; ++i) s += p[(size_t)i * M_];
    c[b * M_ + m] = (s == 0.f) ? 1.f : 1.f / s;
}

__global__ void fused_pair(const float* __restrict__ s,
                           const float* __restrict__ c,
                           float* __restrict__ partial,
                           const int* __restrict__ nrows,
                           const int* __restrict__ ncols) {
    __shared__ float lds[4][M_];
    const int b = blockIdx.y, p = blockIdx.x;
    const int nr = nrows[b], nc = ncols[b];
    const int wave = threadIdx.x >> 6, lane = threadIdx.x & 63;

    const float* cb = c + b * M_;
    float4 cm[4];
    float csum = 0.f;
#pragma unroll
    for (int t = 0; t < 4; ++t) {
        const int m0 = t * 256 + lane * 4;
        float4 v = *reinterpret_cast<const float4*>(cb + m0);
        v.x = (m0 + 0 < nc) ? v.x : 0.f;
        v.y = (m0 + 1 < nc) ? v.y : 0.f;
        v.z = (m0 + 2 < nc) ? v.z : 0.f;
        v.w = (m0 + 3 < nc) ? v.w : 0.f;
        cm[t] = v;
        csum += v.x + v.y + v.z + v.w;
    }
    const int ntiles = (nc + 255) >> 8;

    float4 ca[4];
#pragma unroll
    for (int t = 0; t < 4; ++t) ca[t] = float4{0.f, 0.f, 0.f, 0.f};
    float sr = 0.f;

    const int rbeg = p * RPC + wave * 16;
    const int rend = min(rbeg + 16, nr);
    const float* sb = s + (size_t)b * N_ * M_;

    for (int n = rbeg; n < rend; ++n) {
        float4 v[4];
#pragma unroll
        for (int t = 0; t < 4; ++t) v[t] = float4{0.f, 0.f, 0.f, 0.f};
        float acc = EPS_ * csum;
#pragma unroll
        for (int t = 0; t < 4; ++t) {
            if (t < ntiles) {
                v[t] = *reinterpret_cast<const float4*>(sb + (size_t)n * M_ + t * 256 + lane * 4);
                acc = fmaf(v[t].x, cm[t].x, acc); acc = fmaf(v[t].y, cm[t].y, acc);
                acc = fmaf(v[t].z, cm[t].z, acc); acc = fmaf(v[t].w, cm[t].w, acc);
            }
        }
#pragma unroll
        for (int off = 1; off < 64; off <<= 1)
            acc += __shfl_xor(acc, off, 64);
        const float rn = 1.f / acc;
        sr += rn;
#pragma unroll
        for (int t = 0; t < 4; ++t) {
            ca[t].x = fmaf(v[t].x, rn, ca[t].x);
            ca[t].y = fmaf(v[t].y, rn, ca[t].y);
            ca[t].z = fmaf(v[t].z, rn, ca[t].z);
            ca[t].w = fmaf(v[t].w, rn, ca[t].w);
        }
    }
    {
        const float e = EPS_ * sr;
#pragma unroll
        for (int t = 0; t < 4; ++t) {
            ca[t].x += e; ca[t].y += e; ca[t].z += e; ca[t].w += e;
        }
    }
#pragma unroll
    for (int t = 0; t < 4; ++t)
        *reinterpret_cast<float4*>(&lds[wave][t * 256 + lane * 4]) = ca[t];
    __syncthreads();
    const int m0 = threadIdx.x * 4;
    float4 a0 = *reinterpret_cast<const float4*>(&lds[0][m0]);
    float4 a1 = *reinterpret_cast<const float4*>(&lds[1][m0]);
    float4 a2 = *reinterpret_cast<const float4*>(&lds[2][m0]);
    float4 a3 = *reinterpret_cast<const float4*>(&lds[3][m0]);
    float4 o;
    o.x = a0.x + a1.x + a2.x + a3.x;
    o.y = a0.y + a1.y + a2.y + a3.y;
    o.z = a0.z + a1.z + a2.z + a3.z;
    o.w = a0.w + a1.w + a2.w + a3.w;
    *reinterpret_cast<float4*>(partial + ((size_t)b * PCHUNK + p) * M_ + m0) = o;
}

__global__ void final_fused(const float* __restrict__ s,
                            const float* __restrict__ c,
                            float* __restrict__ out,
                            const int* __restrict__ nrows,
                            const int* __restrict__ ncols) {
    const int b = blockIdx.y;
    const int nr = nrows[b], nc = ncols[b];
    const int wave = threadIdx.x >> 6, lane = threadIdx.x & 63;

    const float* cb = c + b * M_;
    float4 cm[4];
    float csum = 0.f;
#pragma unroll
    for (int t = 0; t < 4; ++t) {
        const int m0 = t * 256 + lane * 4;
        float4 v = *reinterpret_cast<const float4*>(cb + m0);
        v.x = (m0 + 0 < nc) ? v.x : 0.f;
        v.y = (m0 + 1 < nc) ? v.y : 0.f;
        v.z = (m0 + 2 < nc) ? v.z : 0.f;
        v.w = (m0 + 3 < nc) ? v.w : 0.f;
        cm[t] = v;
        csum += v.x + v.y + v.z + v.w;
    }
    const int ntiles = (nc + 255) >> 8;
    const int row0 = blockIdx.x * 16 + wave * 4;
    const float* sb = s + (size_t)b * N_ * M_;
    float* ob = out + (size_t)b * N_ * M_;

    for (int i = 0; i < 4; ++i) {
        const int n = row0 + i;
        if (n >= nr) {
            const float4 z = {0.f, 0.f, 0.f, 0.f};
#pragma unroll
            for (int t = 0; t < 4; ++t)
                *reinterpret_cast<float4*>(ob + (size_t)n * M_ + t * 256 + lane * 4) = z;
            continue;
        }
        float4 v[4];
#pragma unroll
        for (int t = 0; t < 4; ++t) v[t] = float4{0.f, 0.f, 0.f, 0.f};
        float acc = EPS_ * csum;
#pragma unroll
        for (int t = 0; t < 4; ++t) {
            if (t < ntiles) {
                v[t] = *reinterpret_cast<const float4*>(sb + (size_t)n * M_ + t * 256 + lane * 4);
                acc = fmaf(v[t].x, cm[t].x, acc); acc = fmaf(v[t].y, cm[t].y, acc);
                acc = fmaf(v[t].z, cm[t].z, acc); acc = fmaf(v[t].w, cm[t].w, acc);
            }
        }
#pragma unroll
        for (int off = 1; off < 64; off <<= 1)
            acc += __shfl_xor(acc, off, 64);
        const float rn = 1.f / acc;
#pragma unroll
        for (int t = 0; t < 4; ++t) {
            float4 o;
            o.x = (v[t].x + EPS_) * rn * cm[t].x;
            o.y = (v[t].y + EPS_) * rn * cm[t].y;
            o.z = (v[t].z + EPS_) * rn * cm[t].z;
            o.w = (v[t].w + EPS_) * rn * cm[t].w;
            *reinterpret_cast<float4*>(ob + (size_t)n * M_ + t * 256 + lane * 4) = o;
        }
    }
}

// ---------------------------------------------------------------------------
extern "C" void kernel_launch(void* const* d_in, const int* in_sizes, int n_in,
                              void* d_out, int out_size, void* d_ws, size_t ws_size,
                              hipStream_t stream) {
    const float* s = (const float*)d_in[0];
    const int* nrows = (const int*)d_in[1];
    const int* ncols = (const int*)d_in[2];
    float* out = (float*)d_out;

    const size_t qbytes = (size_t)B_ * N_ * M_ * sizeof(__half);      // 128 MiB
    const size_t pbytes = (size_t)B_ * PCHUNK * M_ * sizeof(float);   // 4 MiB
    const dim3 blk(256);
    const dim3 g_chunk(PCHUNK, B_);

    if (ws_size >= qbytes + 2 * pbytes) {
        // fp16 path: 6 dispatches
        __half* q = (__half*)d_ws;
        float* pa = (float*)((char*)d_ws + qbytes);
        float* pb = pa + (size_t)B_ * PCHUNK * M_;

        prep_pass<<<g_chunk, blk, 0, stream>>>(s, q, pa, nrows, ncols);
        fused_pass_h<<<g_chunk, blk, 0, stream>>>(q, pa, pb, nrows, ncols);  // c0 -> r1 -> p(c2)
        fused_pass_h<<<g_chunk, blk, 0, stream>>>(q, pb, pa, nrows, ncols);  // c2 -> r3 -> p(c4)
        fused_pass_h<<<g_chunk, blk, 0, stream>>>(q, pa, pb, nrows, ncols);  // c4 -> r5 -> p(c6)
        fused_pass_h<<<g_chunk, blk, 0, stream>>>(q, pb, pa, nrows, ncols);  // c6 -> r7 -> p(c8)
        final_pass_h<<<g_chunk, blk, 0, stream>>>(q, pa, out, nrows, ncols); // c8 -> r9 -> out
    } else {
        // fp32 fallback (R4 structure, 11 dispatches)
        float* partial = (float*)d_ws;
        float* c = partial + (size_t)B_ * PCHUNK * M_;
        const dim3 g_red(M_ / 256, B_);
        const dim3 g_fin(N_ / 16, B_);

        colsum0_partial<<<g_chunk, blk, 0, stream>>>(s, partial, nrows, ncols);
        reduce_colsum<<<g_red, blk, 0, stream>>>(partial, c);
        for (int k = 0; k < 4; ++k) {
            fused_pair<<<g_chunk, blk, 0, stream>>>(s, c, partial, nrows, ncols);
            reduce_colsum<<<g_red, blk, 0, stream>>>(partial, c);
        }
        final_fused<<<g_fin, blk, 0, stream>>>(s, c, out, nrows, ncols);
    }
}